// Round 6
// baseline (42.548 us; speedup 1.0000x reference)
//
#include <hip/hip_runtime.h>

// Problem dims (fixed by harness setup_inputs)
#define NB 4
#define WR 320
#define NH 240
#define WL 320
#define NLEV 4
#define NK 9
#define TW 64
#define NTILES (WL / TW)           // 5
#define RSTRIDE ((size_t)NH * WL)  // 76800 floats
#define NXCD 8
#define NBLK (NB * NTILES * NH)    // 4800

// LDS float offsets. Band for subtile t' (cols w0+16t'..+15) = rows
// [w0+16t'-96, w0+16t'+55] (152 slots, exact). Union over t'=0..3 =
// rect rows [w0-48, w0+55] x 64 cols  +  6 taper ramps x 16 cols.
#define RECT_ROWS 104
#define TOP0 6656  // 48x16  rows [w0-96, w0-49], t'=0
#define TOP1 7424  // 32x16  rows [w0-80, w0-49], t'=1
#define TOP2 7936  // 16x16  rows [w0-64, w0-49], t'=2
#define BOT1 8192  // 16x16  rows [w0+56, w0+71], t'=1
#define BOT2 8448  // 32x16  rows [w0+56, w0+87], t'=2
#define BOT3 8960  // 48x16  rows [w0+56, w0+103], t'=3
#define LDS_FLOATS 9728  // 38912 B -> 4 blocks/CU

typedef const __attribute__((address_space(1))) void* gas_t;
typedef __attribute__((address_space(3))) void* las_t;

__device__ __forceinline__ void gld_lds16(const float* g, float* l) {
  // async global->LDS; LDS dest = wave-uniform base + lane*16 (linear),
  // global SOURCE is per-lane (rect: contiguous 256B rows; ramps: 64B segs)
  __builtin_amdgcn_global_load_lds((gas_t)g, (las_t)l, 16, 0, 0);
}

template <int L>
__device__ __forceinline__ void sample_level(const float* __restrict__ lds,
                                             int c, int w0, float idx_c,
                                             float* __restrict__ outp) {
  const int tp = c >> 4;  // subtile
  const int cl = c & 15;
  const int Wm1 = (WR >> L) - 1;
  const float sc = 1.0f / (float)(1 << L);
  const float fidx = idx_c * sc;

  // band-slot s = (j<<L) - (w0+16tp) + 96, s in [0,152). Regions (all
  // boundaries = 0 mod 8, so a pooling sum never crosses a region):
  //   s < toplen            -> top ramp band   (stride 16)
  //   toplen <= s <= recthi -> rect [104][64]  (stride 64)
  //   s > recthi            -> bottom ramp band (stride 16)
  const int toplen = 48 - 16 * tp;
  const int recthi = 151 - 16 * tp;
  const int topoff = 6656 + 768 * tp - 128 * tp * (tp - 1);
  const int botoff = 8192 + 128 * tp * (tp - 1);
  const int sbase = 96 - w0 - 16 * tp;

  auto pooled = [&](int j) -> float {
    const int s = (j << L) + sbase;
    int a, stride;
    if (s < toplen) {
      a = topoff + s * 16 + cl;
      stride = 16;
    } else if (s <= recthi) {
      a = (s + 16 * tp - 48) * 64 + c;
      stride = 64;
    } else {
      a = botoff + (s - 152 + 16 * tp) * 16 + cl;
      stride = 16;
    }
    float v = lds[a];
#pragma unroll
    for (int t = 1; t < (1 << L); ++t) v += lds[a + t * stride];
    return v * sc;
  };

  // k=0 index; i0 sequence is non-decreasing with steps in {0,1}
  float idk = fminf(fmaxf(fidx - 4.0f, 0.0f), (float)Wm1);
  int j = (int)idk;
  float vA = pooled(j);
  float vB = pooled(min(j + 1, Wm1));

#pragma unroll
  for (int k = 0; k < NK; ++k) {
    const float idx = fminf(fmaxf(fidx + (float)(k - 4), 0.0f), (float)Wm1);
    const int i0 = (int)idx;
    if (i0 != j) {  // slide the (vA,vB) window
      vA = vB;
      vB = pooled(min(i0 + 1, Wm1));
      j = i0;
    }
    const float w = idx - (float)i0;
    outp[(size_t)k * RSTRIDE] = fmaf(w, vB - vA, vA);
  }
}

extern "C" __global__ __launch_bounds__(256, 4) void corr_sample_kernel(
    const float* __restrict__ corr, const float* __restrict__ disp,
    float* __restrict__ out) {
  __shared__ float lds0[LDS_FLOATS];

  // h-fastest decode + bijective XCD chunking: co-resident blocks handle
  // adjacent h of the same (b,tile) -> their reads/writes share DRAM pages.
  const int bid = ((int)blockIdx.x & (NXCD - 1)) * (NBLK / NXCD) +
                  ((int)blockIdx.x >> 3);
  const int h = bid % NH;
  const int rest = bid / NH;
  const int tile = rest % NTILES;
  const int b = rest / NTILES;
  const int w0 = tile * TW;

  const int tid = (int)threadIdx.x;
  const int lane = tid & 63;
  const int wv = tid >> 6;  // wave id == pyramid level (compute phase)

  const size_t bh = (size_t)b * WR * RSTRIDE + (size_t)h * WL;  // (b,r=0,h,0)

  // ---- stage rect: rows [w0-48, w0+55] x cols [w0, w0+64), 26 instrs,
  // each = 4 rows x 256 B contiguous global -> 1 KB linear LDS ----
  for (int i = wv; i < 26; i += 4) {
    const int r0 = w0 - 48 + 4 * i;
    if (r0 >= 0) {  // boundary at 0 is 4-aligned; max row 311 < 320
      const int r = r0 + (lane >> 4);
      const float* src = corr + bh + (size_t)r * RSTRIDE + w0 + ((lane & 15) << 2);
      gld_lds16(src, &lds0[i * 256]);
    }
  }

  // ---- stage 6 taper ramps: 12 instrs, each = 16 slots x 64 B ----
  {
    // per-instr literals: {lds float offset, row base rel w0, subtile}
    const int ROFF[12] = {TOP0, TOP0 + 256, TOP0 + 512, TOP1, TOP1 + 256,
                          TOP2, BOT1,       BOT2,       BOT2 + 256,
                          BOT3, BOT3 + 256, BOT3 + 512};
    const int RREL[12] = {-96, -80, -64, -80, -64, -64, 56, 56, 72, 56, 72, 88};
    const int RTP[12] = {0, 0, 0, 1, 1, 2, 1, 2, 2, 3, 3, 3};
#pragma unroll
    for (int idx = 0; idx < 12; ++idx) {  // idx compile-time (full unroll)
      if ((idx & 3) != wv) continue;      // wave-uniform branch
      const int rowbase = w0 + RREL[idx];
      if (rowbase + 15 >= 0 && rowbase < WR) {  // skip fully-OOB instrs
        int r = rowbase + (lane >> 2);
        r = min(max(r, 0), WR - 1);  // clamp: dup 64B lines, L2 absorbs
        const float* src =
            corr + bh + (size_t)r * RSTRIDE + (w0 + 16 * RTP[idx] + ((lane & 3) << 2));
        gld_lds16(src, &lds0[ROFF[idx]]);
      }
    }
  }

  // disp load issues alongside staging (drained by same vmcnt)
  const int c = lane;
  const float dsp = disp[((size_t)b * NH + h) * WL + w0 + c];

  asm volatile("s_waitcnt vmcnt(0)" ::: "memory");
  __syncthreads();

  // ---- sample: wave wv = level; writes 256 B contiguous per plane ----
  const float idx_c = (float)(w0 + c) - dsp;
  float* outp =
      out + ((size_t)(b * (NLEV * NK) + wv * NK) * NH + h) * WL + w0 + c;

  switch (wv) {
    case 0: sample_level<0>(lds0, c, w0, idx_c, outp); break;
    case 1: sample_level<1>(lds0, c, w0, idx_c, outp); break;
    case 2: sample_level<2>(lds0, c, w0, idx_c, outp); break;
    default: sample_level<3>(lds0, c, w0, idx_c, outp); break;
  }
}

extern "C" void kernel_launch(void* const* d_in, const int* in_sizes, int n_in,
                              void* d_out, int out_size, void* d_ws,
                              size_t ws_size, hipStream_t stream) {
  const float* corr = (const float*)d_in[0];
  const float* disp = (const float*)d_in[1];
  float* out = (float*)d_out;
  corr_sample_kernel<<<NBLK, 256, 0, stream>>>(corr, disp, out);
}